// Round 1
// baseline (482.663 us; speedup 1.0000x reference)
//
#include <hip/hip_runtime.h>

#define M_DIM 8192
#define IN_DIM 4096
#define OUT_DIM 4096

typedef int   v4i __attribute__((ext_vector_type(4)));
typedef short v8s __attribute__((ext_vector_type(8)));
typedef float v4f __attribute__((ext_vector_type(4)));

static __device__ __forceinline__ int pack4(int a, int b, int c, int d) {
    return (a & 255) | ((b & 255) << 8) | ((c & 255) << 16) | ((d & 255) << 24);
}

static __device__ __forceinline__ short f2bf(float f) {
    unsigned u = __float_as_uint(f);
    u = (u + 0x7FFFu + ((u >> 16) & 1u)) >> 16;  // RNE
    return (short)u;
}

// tanh-approx GELU: 0.5u(1+tanh(0.79788456(u+0.044715u^3))) = u - u/(exp(2v)+1)
static __device__ __forceinline__ float gelu_tanh(float u) {
    float u2 = u * u;
    float p  = fmaf(u2, 0.0356774081f, 0.7978845608f);
    float v  = u * p;
    float e  = __builtin_amdgcn_exp2f(v * 2.8853900818f);  // exp(2v)
    float d  = e + 1.0f;
    return u - u * __builtin_amdgcn_rcpf(d);
}

static __device__ __forceinline__ void async_cp16(const signed char* g, signed char* l) {
    __builtin_amdgcn_global_load_lds((const __attribute__((address_space(1))) void*)g,
                                     (__attribute__((address_space(3))) void*)l, 16, 0, 0);
}

// ---------------- kernel 1: pack weight int32 -> int8 ----------------
__global__ __launch_bounds__(256) void pack_w_kernel(const int* __restrict__ w,
                                                     signed char* __restrict__ w8) {
    size_t i = ((size_t)blockIdx.x * 256 + threadIdx.x) * 16;
    const int4* p = (const int4*)(w + i);
    int4 a = p[0], b = p[1], c = p[2], d = p[3];
    int4 o;
    o.x = pack4(a.x, a.y, a.z, a.w);
    o.y = pack4(b.x, b.y, b.z, b.w);
    o.z = pack4(c.x, c.y, c.z, c.w);
    o.w = pack4(d.x, d.y, d.z, d.w);
    *(int4*)(w8 + i) = o;
}

// ------- kernel 2: pack x int32 -> int8 AND T[m][r] = sum_k x[m][k]*A[r][k] -------
// block = 256 threads, 4 rows per block; thread t owns k-chunk [t*16, t*16+16)
__global__ __launch_bounds__(256) void pack_x_lora_kernel(const int* __restrict__ x,
                                                          const float* __restrict__ la,
                                                          signed char* __restrict__ x8,
                                                          float* __restrict__ T) {
    __shared__ float red[64 * 257];
    const int t    = threadIdx.x;
    const int row0 = blockIdx.x * 4;
    const int k0   = t * 16;

    float xf[4][16];
#pragma unroll
    for (int g = 0; g < 4; ++g) {
        const int4* xp = (const int4*)(x + (size_t)(row0 + g) * IN_DIM + k0);
        int4 a = xp[0], b = xp[1], c = xp[2], d = xp[3];
        int4 o;
        o.x = pack4(a.x, a.y, a.z, a.w);
        o.y = pack4(b.x, b.y, b.z, b.w);
        o.z = pack4(c.x, c.y, c.z, c.w);
        o.w = pack4(d.x, d.y, d.z, d.w);
        *(int4*)(x8 + (size_t)(row0 + g) * IN_DIM + k0) = o;
        xf[g][0]=(float)a.x;  xf[g][1]=(float)a.y;  xf[g][2]=(float)a.z;  xf[g][3]=(float)a.w;
        xf[g][4]=(float)b.x;  xf[g][5]=(float)b.y;  xf[g][6]=(float)b.z;  xf[g][7]=(float)b.w;
        xf[g][8]=(float)c.x;  xf[g][9]=(float)c.y;  xf[g][10]=(float)c.z; xf[g][11]=(float)c.w;
        xf[g][12]=(float)d.x; xf[g][13]=(float)d.y; xf[g][14]=(float)d.z; xf[g][15]=(float)d.w;
    }

    float acc[4][16];
#pragma unroll
    for (int g = 0; g < 4; ++g)
#pragma unroll
        for (int r = 0; r < 16; ++r) acc[g][r] = 0.0f;

#pragma unroll
    for (int r = 0; r < 16; ++r) {
        const float4* ap = (const float4*)(la + (size_t)r * IN_DIM + k0);
        float4 a0 = ap[0], a1 = ap[1], a2 = ap[2], a3 = ap[3];
        float av[16] = {a0.x,a0.y,a0.z,a0.w, a1.x,a1.y,a1.z,a1.w,
                        a2.x,a2.y,a2.z,a2.w, a3.x,a3.y,a3.z,a3.w};
#pragma unroll
        for (int g = 0; g < 4; ++g) {
#pragma unroll
            for (int j = 0; j < 16; ++j) acc[g][r] = fmaf(xf[g][j], av[j], acc[g][r]);
        }
    }

#pragma unroll
    for (int g = 0; g < 4; ++g)
#pragma unroll
        for (int r = 0; r < 16; ++r) red[(g * 16 + r) * 257 + t] = acc[g][r];
    __syncthreads();

    if (t < 64) {
        float s = 0.0f;
        for (int tt = 0; tt < 256; ++tt) s += red[t * 257 + tt];
        T[(size_t)(row0 + (t >> 4)) * 16 + (t & 15)] = s;
    }
}

// ---------------- kernel 3: i8 MFMA GEMM + fused LoRA/bias/GELU epilogue ----------------
// 128x128 tile, BK=64, 4 waves, wave tile 64x64 (4x4 of 16x16x64 i8 MFMA)
__global__ __launch_bounds__(256) void q8_gemm_kernel(
    const signed char* __restrict__ x8, const signed char* __restrict__ w8,
    const float* __restrict__ T, const float* __restrict__ lb,
    const float* __restrict__ bias, const float* __restrict__ xsc,
    const float* __restrict__ wsc, const int* __restrict__ gflag,
    float* __restrict__ out) {
    __shared__ __align__(16) signed char Ald[128 * 64];
    __shared__ __align__(16) signed char Bld[128 * 64];
    __shared__ __align__(16) short Tb[128 * 32];
    __shared__ __align__(16) short Bb[128 * 32];
    __shared__ float xs_t[128], ws_t[128], bias_t[128];

    const int tid  = threadIdx.x;
    const int lane = tid & 63;
    const int wv   = tid >> 6;
    const int wm   = wv >> 1;
    const int wn   = wv & 1;
    const int bn   = blockIdx.x & 31;
    const int bm   = blockIdx.x >> 5;

    const int frow = lane & 15;
    const int fq   = lane >> 4;

    // staging map: wave wv loads rows [wv*32, wv*32+32); lane l -> row +l/4, 16B chunk l%4
    const int srow = wv * 32 + (lane >> 2);
    const int scol = (lane & 3) * 16;
    const signed char* ag0 = x8 + (size_t)(bm * 128 + srow) * IN_DIM + scol;
    const signed char* ag1 = ag0 + 16 * IN_DIM;
    const signed char* bg0 = w8 + (size_t)(bn * 128 + srow) * IN_DIM + scol;
    const signed char* bg1 = bg0 + 16 * IN_DIM;
    signed char* al0 = &Ald[wv * 2048];
    signed char* al1 = al0 + 1024;
    signed char* bl0 = &Bld[wv * 2048];
    signed char* bl1 = bl0 + 1024;

    v4i acc[4][4];
#pragma unroll
    for (int i = 0; i < 4; ++i)
#pragma unroll
        for (int j = 0; j < 4; ++j) acc[i][j] = 0;

    const int abase = (wm * 64 + frow) * 64 + fq * 16;
    const int bbase = (wn * 64 + frow) * 64 + fq * 16;

    for (int kk = 0; kk < IN_DIM / 64; ++kk) {
        __syncthreads();
        const size_t ko = (size_t)kk * 64;
        async_cp16(ag0 + ko, al0);
        async_cp16(ag1 + ko, al1);
        async_cp16(bg0 + ko, bl0);
        async_cp16(bg1 + ko, bl1);
        __syncthreads();  // drains vmcnt(0) before s_barrier

        v4i av[4], bv[4];
#pragma unroll
        for (int mt = 0; mt < 4; ++mt) av[mt] = *(const v4i*)(Ald + abase + mt * 1024);
#pragma unroll
        for (int nt = 0; nt < 4; ++nt) bv[nt] = *(const v4i*)(Bld + bbase + nt * 1024);
#pragma unroll
        for (int mt = 0; mt < 4; ++mt)
#pragma unroll
            for (int nt = 0; nt < 4; ++nt)
                acc[mt][nt] = __builtin_amdgcn_mfma_i32_16x16x64_i8(av[mt], bv[nt],
                                                                    acc[mt][nt], 0, 0, 0);
    }

    // ---- epilogue staging: T-tile / lora_b-tile as bf16 (K padded 16->32 with zeros) ----
    {
        const int row = tid >> 1, half = tid & 1;
        const float4* tp = (const float4*)(T + (size_t)(bm * 128 + row) * 16 + half * 8);
        float4 f0 = tp[0], f1 = tp[1];
        short* dst = &Tb[row * 32 + half * 8];
        dst[0] = f2bf(f0.x); dst[1] = f2bf(f0.y); dst[2] = f2bf(f0.z); dst[3] = f2bf(f0.w);
        dst[4] = f2bf(f1.x); dst[5] = f2bf(f1.y); dst[6] = f2bf(f1.z); dst[7] = f2bf(f1.w);
        short* dz = &Tb[row * 32 + 16 + half * 8];
#pragma unroll
        for (int j = 0; j < 8; ++j) dz[j] = 0;

        const float4* bp = (const float4*)(lb + (size_t)(bn * 128 + row) * 16 + half * 8);
        float4 g0 = bp[0], g1 = bp[1];
        short* db = &Bb[row * 32 + half * 8];
        db[0] = f2bf(g0.x); db[1] = f2bf(g0.y); db[2] = f2bf(g0.z); db[3] = f2bf(g0.w);
        db[4] = f2bf(g1.x); db[5] = f2bf(g1.y); db[6] = f2bf(g1.z); db[7] = f2bf(g1.w);
        short* dbz = &Bb[row * 32 + 16 + half * 8];
#pragma unroll
        for (int j = 0; j < 8; ++j) dbz[j] = 0;
    }
    if (tid < 128) {
        xs_t[tid]   = xsc[bm * 128 + tid];
        ws_t[tid]   = wsc[bn * 128 + tid];
        bias_t[tid] = bias[bn * 128 + tid];
    }
    __syncthreads();

    const bool dg = (*gflag) != 0;

    v8s tb[4], bbf[4];
#pragma unroll
    for (int mt = 0; mt < 4; ++mt)
        tb[mt] = *(const v8s*)(&Tb[(wm * 64 + mt * 16 + frow) * 32 + fq * 8]);
#pragma unroll
    for (int nt = 0; nt < 4; ++nt)
        bbf[nt] = *(const v8s*)(&Bb[(wn * 64 + nt * 16 + frow) * 32 + fq * 8]);

#pragma unroll
    for (int mt = 0; mt < 4; ++mt) {
#pragma unroll
        for (int nt = 0; nt < 4; ++nt) {
            const int ncol  = wn * 64 + nt * 16 + frow;
            const float wsv = ws_t[ncol];
            const float bv  = bias_t[ncol];
            v4f fa;
            fa[0] = (float)acc[mt][nt][0] * wsv;
            fa[1] = (float)acc[mt][nt][1] * wsv;
            fa[2] = (float)acc[mt][nt][2] * wsv;
            fa[3] = (float)acc[mt][nt][3] * wsv;
            // fa = acc*ws + sum_r T[m,r]*lora_b[n,r]   (C/D layout shared with i8 MFMA)
            fa = __builtin_amdgcn_mfma_f32_16x16x32_bf16(tb[mt], bbf[nt], fa, 0, 0, 0);
#pragma unroll
            for (int r = 0; r < 4; ++r) {
                const int ml = wm * 64 + mt * 16 + fq * 4 + r;
                float u = fmaf(xs_t[ml], fa[r], bv);
                if (dg) u = gelu_tanh(u);
                out[(size_t)(bm * 128 + ml) * OUT_DIM + bn * 128 + ncol] = u;
            }
        }
    }
}

extern "C" void kernel_launch(void* const* d_in, const int* in_sizes, int n_in,
                              void* d_out, int out_size, void* d_ws, size_t ws_size,
                              hipStream_t stream) {
    const int*   x     = (const int*)d_in[0];
    const int*   wt    = (const int*)d_in[1];
    const float* bias  = (const float*)d_in[2];
    const float* xsc   = (const float*)d_in[3];
    const float* wsc   = (const float*)d_in[4];
    const float* la    = (const float*)d_in[5];
    const float* lb    = (const float*)d_in[6];
    const int*   gflag = (const int*)d_in[7];
    float* out = (float*)d_out;

    signed char* x8 = (signed char*)d_ws;
    signed char* w8 = x8 + (size_t)M_DIM * IN_DIM;
    float* T = (float*)(w8 + (size_t)OUT_DIM * IN_DIM);

    pack_w_kernel<<<(OUT_DIM * (size_t)IN_DIM) / (16 * 256), 256, 0, stream>>>(wt, w8);
    pack_x_lora_kernel<<<M_DIM / 4, 256, 0, stream>>>(x, la, x8, T);
    q8_gemm_kernel<<<(M_DIM / 128) * (OUT_DIM / 128), 256, 0, stream>>>(
        x8, w8, T, lb, bias, xsc, wsc, gflag, out);
}

// Round 2
// 454.463 us; speedup vs baseline: 1.0621x; 1.0621x over previous
//
#include <hip/hip_runtime.h>

#define M_DIM 8192
#define IN_DIM 4096
#define OUT_DIM 4096

typedef int   v4i __attribute__((ext_vector_type(4)));
typedef short v8s __attribute__((ext_vector_type(8)));
typedef float v4f __attribute__((ext_vector_type(4)));

static __device__ __forceinline__ int pack4(int a, int b, int c, int d) {
    return (a & 255) | ((b & 255) << 8) | ((c & 255) << 16) | ((d & 255) << 24);
}

static __device__ __forceinline__ short f2bf(float f) {  // RNE
    unsigned u = __float_as_uint(f);
    u = (u + 0x7FFFu + ((u >> 16) & 1u)) >> 16;
    return (short)u;
}

static __device__ __forceinline__ short i2bf(int v) {  // exact for |v| <= 128
    float f = (float)v;
    return (short)(__float_as_uint(f) >> 16);
}

// tanh-approx GELU: u - u/(exp(2*0.7978845608*(u+0.044715u^3))+1)
static __device__ __forceinline__ float gelu_tanh(float u) {
    float u2 = u * u;
    float p  = fmaf(u2, 0.0356774081f, 0.7978845608f);
    float v  = u * p;
    float e  = __builtin_amdgcn_exp2f(v * 2.8853900818f);
    return u - u * __builtin_amdgcn_rcpf(e + 1.0f);
}

static __device__ __forceinline__ void async_cp16(const signed char* g, signed char* l) {
    __builtin_amdgcn_global_load_lds((const __attribute__((address_space(1))) void*)g,
                                     (__attribute__((address_space(3))) void*)l, 16, 0, 0);
}

// ---------------- pack int32 -> int8, 16 elems/thread, fully coalesced ----------------
__global__ __launch_bounds__(256) void pack_i32_i8_kernel(const int* __restrict__ src,
                                                          signed char* __restrict__ dst) {
    const int t = threadIdx.x;
    const size_t blk = (size_t)blockIdx.x;
    const int4* p = (const int4*)src + blk * 1024;
    int* q = (int*)dst + blk * 1024;
    int4 v0 = p[t], v1 = p[256 + t], v2 = p[512 + t], v3 = p[768 + t];
    q[t]       = pack4(v0.x, v0.y, v0.z, v0.w);
    q[256 + t] = pack4(v1.x, v1.y, v1.z, v1.w);
    q[512 + t] = pack4(v2.x, v2.y, v2.z, v2.w);
    q[768 + t] = pack4(v3.x, v3.y, v3.z, v3.w);
}

// ---------------- lora_a fp32 -> bf16 (RNE) ----------------
__global__ __launch_bounds__(256) void pack_a_kernel(const float* __restrict__ la,
                                                     short* __restrict__ a16) {
    size_t i = ((size_t)blockIdx.x * 256 + threadIdx.x) * 8;
    const float4* p = (const float4*)(la + i);
    float4 a = p[0], b = p[1];
    v8s o;
    o[0] = f2bf(a.x); o[1] = f2bf(a.y); o[2] = f2bf(a.z); o[3] = f2bf(a.w);
    o[4] = f2bf(b.x); o[5] = f2bf(b.y); o[6] = f2bf(b.z); o[7] = f2bf(b.w);
    *(v8s*)(a16 + i) = o;
}

// ------- T[m][r] = sum_k x[m][k]*A[r][k] via bf16 MFMA (x int8 -> bf16 exact) -------
// block: 4 waves, 16 rows; wave wv covers k in [wv*1024, wv*1024+1024); grid 512
__global__ __launch_bounds__(256) void lora_t_kernel(const signed char* __restrict__ x8,
                                                     const short* __restrict__ a16,
                                                     float* __restrict__ T) {
    __shared__ float red[4 * 256];
    const int tid = threadIdx.x;
    const int lane = tid & 63, wv = tid >> 6;
    const int fr = lane & 15, fq = lane >> 4;
    const int m0 = blockIdx.x * 16;

    const signed char* bx = x8 + (size_t)(m0 + fr) * IN_DIM + wv * 1024 + fq * 8;
    const short*       ba = a16 + (size_t)fr * IN_DIM + wv * 1024 + fq * 8;

    v4f acc = {0.f, 0.f, 0.f, 0.f};
#pragma unroll 4
    for (int kt = 0; kt < 32; ++kt) {
        int2 w = *(const int2*)(bx + kt * 32);
        int lo = w.x, hi = w.y;
        v8s xa;
        xa[0] = i2bf((lo << 24) >> 24); xa[1] = i2bf((lo << 16) >> 24);
        xa[2] = i2bf((lo << 8) >> 24);  xa[3] = i2bf(lo >> 24);
        xa[4] = i2bf((hi << 24) >> 24); xa[5] = i2bf((hi << 16) >> 24);
        xa[6] = i2bf((hi << 8) >> 24);  xa[7] = i2bf(hi >> 24);
        v8s aa = *(const v8s*)(ba + kt * 32);
        acc = __builtin_amdgcn_mfma_f32_16x16x32_bf16(xa, aa, acc, 0, 0, 0);
    }
    *(v4f*)&red[wv * 256 + lane * 4] = acc;
    __syncthreads();

    float s = red[tid] + red[256 + tid] + red[512 + tid] + red[768 + tid];
    int sl = tid >> 2, j = tid & 3;
    int row = ((sl >> 4) << 2) + j, col = sl & 15;  // C/D: col=lane&15, row=quad*4+reg
    T[(size_t)(m0 + row) * 16 + col] = s;
}

// ---------------- i8 MFMA GEMM, double-buffered LDS, fused LoRA/bias/GELU ----------------
// 128x128 tile, BK=64, 4 waves x (4x4 of 16x16x64 i8 MFMA); epilogue overlays staging LDS
__global__ __launch_bounds__(256, 4) void q8_gemm_kernel(
    const signed char* __restrict__ x8, const signed char* __restrict__ w8,
    const float* __restrict__ T, const float* __restrict__ lb,
    const float* __restrict__ bias, const float* __restrict__ xsc,
    const float* __restrict__ wsc, const int* __restrict__ gflag,
    float* __restrict__ out) {
    __shared__ __align__(16) signed char smem[32768];  // buf0: A[0,8K) B[8K,16K); buf1: +16K

    const int tid  = threadIdx.x;
    const int lane = tid & 63;
    const int wv   = tid >> 6;
    const int wm   = wv >> 1;
    const int wn   = wv & 1;
    const int bn   = blockIdx.x & 31;
    const int bm   = blockIdx.x >> 5;
    const int fr   = lane & 15;
    const int fq   = lane >> 4;

    // staging: wave wv loads rows [wv*32,+32); lane l -> row l>>2 (+16 for 2nd load),
    // global 16B chunk XOR-swizzled so frag reads are 4-way instead of 8-way conflicted
    const int srow = wv * 32 + (lane >> 2);
    const int scol = (((lane & 3) ^ ((lane >> 2) & 3)) & 3) * 16;
    const signed char* ag0 = x8 + (size_t)(bm * 128 + srow) * IN_DIM + scol;
    const signed char* ag1 = ag0 + 16 * IN_DIM;
    const signed char* bg0 = w8 + (size_t)(bn * 128 + srow) * IN_DIM + scol;
    const signed char* bg1 = bg0 + 16 * IN_DIM;
    signed char* sA0 = smem + wv * 2048;
    signed char* sB0 = smem + 8192 + wv * 2048;
    signed char* sA1 = smem + 16384 + wv * 2048;
    signed char* sB1 = smem + 24576 + wv * 2048;

    v4i acc[4][4];
#pragma unroll
    for (int i = 0; i < 4; ++i)
#pragma unroll
        for (int j = 0; j < 4; ++j) acc[i][j] = 0;

    const int rot    = ((fq ^ fr) & 3) * 16;
    const int abase0 = (wm * 64 + fr) * 64 + rot;
    const int bbase0 = (wn * 64 + fr) * 64 + rot;

    // preload tile 0 -> buf0
    async_cp16(ag0, sA0); async_cp16(ag1, sA0 + 1024);
    async_cp16(bg0, sB0); async_cp16(bg1, sB0 + 1024);

#pragma unroll 2
    for (int kk = 0; kk < 64; ++kk) {
        __syncthreads();  // vmcnt(0) drain: buf[kk&1] ready; all reads of other buf done
        if (kk + 1 < 64) {
            const size_t ko = (size_t)(kk + 1) * 64;
            if (kk & 1) {
                async_cp16(ag0 + ko, sA0); async_cp16(ag1 + ko, sA0 + 1024);
                async_cp16(bg0 + ko, sB0); async_cp16(bg1 + ko, sB0 + 1024);
            } else {
                async_cp16(ag0 + ko, sA1); async_cp16(ag1 + ko, sA1 + 1024);
                async_cp16(bg0 + ko, sB1); async_cp16(bg1 + ko, sB1 + 1024);
            }
        }
        const signed char* Ab = smem + ((kk & 1) ? 16384 : 0);
        const signed char* Bb = Ab + 8192;

        v4i av[4], bv[4];
#pragma unroll
        for (int mt = 0; mt < 4; ++mt) av[mt] = *(const v4i*)(Ab + abase0 + mt * 1024);
#pragma unroll
        for (int nt = 0; nt < 4; ++nt) bv[nt] = *(const v4i*)(Bb + bbase0 + nt * 1024);
#pragma unroll
        for (int mt = 0; mt < 4; ++mt)
#pragma unroll
            for (int nt = 0; nt < 4; ++nt)
                acc[mt][nt] = __builtin_amdgcn_mfma_i32_16x16x64_i8(av[mt], bv[nt],
                                                                    acc[mt][nt], 0, 0, 0);
    }

    __syncthreads();  // staging fully consumed; overlay epilogue data into smem
    short* Tb     = (short*)smem;            // 128 x 32 bf16 (K padded 16->32 w/ zeros)
    short* Bbs    = (short*)(smem + 8192);   // 128 x 32 bf16
    float* xs_t   = (float*)(smem + 16384);
    float* ws_t   = xs_t + 128;
    float* bias_t = ws_t + 128;

    {
        const int row = tid >> 1, half = tid & 1;
        const float4* tp = (const float4*)(T + (size_t)(bm * 128 + row) * 16 + half * 8);
        float4 f0 = tp[0], f1 = tp[1];
        short* dst = &Tb[row * 32 + half * 8];
        dst[0] = f2bf(f0.x); dst[1] = f2bf(f0.y); dst[2] = f2bf(f0.z); dst[3] = f2bf(f0.w);
        dst[4] = f2bf(f1.x); dst[5] = f2bf(f1.y); dst[6] = f2bf(f1.z); dst[7] = f2bf(f1.w);
        short* dz = &Tb[row * 32 + 16 + half * 8];
#pragma unroll
        for (int j = 0; j < 8; ++j) dz[j] = 0;

        const float4* bp = (const float4*)(lb + (size_t)(bn * 128 + row) * 16 + half * 8);
        float4 g0 = bp[0], g1 = bp[1];
        short* db = &Bbs[row * 32 + half * 8];
        db[0] = f2bf(g0.x); db[1] = f2bf(g0.y); db[2] = f2bf(g0.z); db[3] = f2bf(g0.w);
        db[4] = f2bf(g1.x); db[5] = f2bf(g1.y); db[6] = f2bf(g1.z); db[7] = f2bf(g1.w);
        short* dbz = &Bbs[row * 32 + 16 + half * 8];
#pragma unroll
        for (int j = 0; j < 8; ++j) dbz[j] = 0;
    }
    if (tid < 128) {
        xs_t[tid]   = xsc[bm * 128 + tid];
        ws_t[tid]   = wsc[bn * 128 + tid];
        bias_t[tid] = bias[bn * 128 + tid];
    }
    __syncthreads();

    const bool dg = (*gflag) != 0;

    v8s tb[4], bbf[4];
#pragma unroll
    for (int mt = 0; mt < 4; ++mt)
        tb[mt] = *(const v8s*)(&Tb[(wm * 64 + mt * 16 + fr) * 32 + fq * 8]);
#pragma unroll
    for (int nt = 0; nt < 4; ++nt)
        bbf[nt] = *(const v8s*)(&Bbs[(wn * 64 + nt * 16 + fr) * 32 + fq * 8]);

#pragma unroll
    for (int mt = 0; mt < 4; ++mt) {
#pragma unroll
        for (int nt = 0; nt < 4; ++nt) {
            const int ncol  = wn * 64 + nt * 16 + fr;
            const float wsv = ws_t[ncol];
            const float bv  = bias_t[ncol];
            v4f fa;
            fa[0] = (float)acc[mt][nt][0] * wsv;
            fa[1] = (float)acc[mt][nt][1] * wsv;
            fa[2] = (float)acc[mt][nt][2] * wsv;
            fa[3] = (float)acc[mt][nt][3] * wsv;
            // fa = acc*ws + sum_r T[m,r]*lora_b[n,r]  (same C/D layout as i8 MFMA)
            fa = __builtin_amdgcn_mfma_f32_16x16x32_bf16(tb[mt], bbf[nt], fa, 0, 0, 0);
#pragma unroll
            for (int r = 0; r < 4; ++r) {
                const int ml = wm * 64 + mt * 16 + fq * 4 + r;
                float u = fmaf(xs_t[ml], fa[r], bv);
                if (dg) u = gelu_tanh(u);
                out[(size_t)(bm * 128 + ml) * OUT_DIM + bn * 128 + ncol] = u;
            }
        }
    }
}

extern "C" void kernel_launch(void* const* d_in, const int* in_sizes, int n_in,
                              void* d_out, int out_size, void* d_ws, size_t ws_size,
                              hipStream_t stream) {
    const int*   x     = (const int*)d_in[0];
    const int*   wt    = (const int*)d_in[1];
    const float* bias  = (const float*)d_in[2];
    const float* xsc   = (const float*)d_in[3];
    const float* wsc   = (const float*)d_in[4];
    const float* la    = (const float*)d_in[5];
    const float* lb    = (const float*)d_in[6];
    const int*   gflag = (const int*)d_in[7];
    float* out = (float*)d_out;

    signed char* x8 = (signed char*)d_ws;
    signed char* w8 = x8 + (size_t)M_DIM * IN_DIM;
    float* T = (float*)(w8 + (size_t)OUT_DIM * IN_DIM);
    // a16 aliases the w8 region: it is consumed by lora_t BEFORE pack_w writes w8
    short* a16 = (short*)w8;

    pack_i32_i8_kernel<<<(size_t)M_DIM * IN_DIM / 4096, 256, 0, stream>>>(x, x8);
    pack_a_kernel<<<16 * IN_DIM / (8 * 256), 256, 0, stream>>>(la, a16);
    lora_t_kernel<<<M_DIM / 16, 256, 0, stream>>>(x8, a16, T);
    pack_i32_i8_kernel<<<(size_t)OUT_DIM * IN_DIM / 4096, 256, 0, stream>>>(wt, w8);
    q8_gemm_kernel<<<(M_DIM / 128) * (OUT_DIM / 128), 256, 0, stream>>>(
        x8, w8, T, lb, bias, xsc, wsc, gflag, out);
}

// Round 3
// 442.920 us; speedup vs baseline: 1.0897x; 1.0261x over previous
//
#include <hip/hip_runtime.h>

#define M_DIM 8192
#define IN_DIM 4096
#define OUT_DIM 4096

typedef int   v4i  __attribute__((ext_vector_type(4)));
typedef int   v16i __attribute__((ext_vector_type(16)));
typedef short v8s  __attribute__((ext_vector_type(8)));
typedef float v4f  __attribute__((ext_vector_type(4)));
typedef float v16f __attribute__((ext_vector_type(16)));

static __device__ __forceinline__ int pack4(int a, int b, int c, int d) {
    return (a & 255) | ((b & 255) << 8) | ((c & 255) << 16) | ((d & 255) << 24);
}

static __device__ __forceinline__ short f2bf(float f) {  // RNE
    unsigned u = __float_as_uint(f);
    u = (u + 0x7FFFu + ((u >> 16) & 1u)) >> 16;
    return (short)u;
}

static __device__ __forceinline__ short i2bf(int v) {  // exact for |v| <= 128
    float f = (float)v;
    return (short)(__float_as_uint(f) >> 16);
}

static __device__ __forceinline__ float gelu_tanh(float u) {
    float u2 = u * u;
    float p  = fmaf(u2, 0.0356774081f, 0.7978845608f);
    float v  = u * p;
    float e  = __builtin_amdgcn_exp2f(v * 2.8853900818f);
    return u - u * __builtin_amdgcn_rcpf(e + 1.0f);
}

static __device__ __forceinline__ void async_cp16(const signed char* g, signed char* l) {
    __builtin_amdgcn_global_load_lds((const __attribute__((address_space(1))) void*)g,
                                     (__attribute__((address_space(3))) void*)l, 16, 0, 0);
}

// Tiled operand layout (shared by pack kernels and GEMM staging):
//   buf[((tile*64 + kk)*16 + gp)*1024 + lane*16 + j] = src[row][k]
//   row = tile*256 + (gp>>1)*32 + (lane&31)
//   k   = kk*64 + (gp&1)*32 + (lane>>5)*16 + j ,  j in [0,16)
// This makes GEMM staging reads 1KB-contiguous and frag ds_read_b128 = base+lane*16.

// ---------------- lora_a fp32 -> bf16 ----------------
__global__ __launch_bounds__(256) void pack_a_kernel(const float* __restrict__ la,
                                                     short* __restrict__ a16) {
    size_t i = ((size_t)blockIdx.x * 256 + threadIdx.x) * 8;
    const float4* p = (const float4*)(la + i);
    float4 a = p[0], b = p[1];
    v8s o;
    o[0] = f2bf(a.x); o[1] = f2bf(a.y); o[2] = f2bf(a.z); o[3] = f2bf(a.w);
    o[4] = f2bf(b.x); o[5] = f2bf(b.y); o[6] = f2bf(b.z); o[7] = f2bf(b.w);
    *(v8s*)(a16 + i) = o;
}

// ---------------- weight int32 -> int8 in tiled layout (gather) ----------------
__global__ __launch_bounds__(256) void pack_w_kernel(const int* __restrict__ w,
                                                     signed char* __restrict__ w8t) {
    const int flat = blockIdx.x * 256 + threadIdx.x;  // 16B slot id
    const int l  = flat & 63;
    const int gp = (flat >> 6) & 15;
    const int kk = (flat >> 10) & 63;
    const int bn = flat >> 16;
    const int n = bn * 256 + ((gp >> 1) << 5) + (l & 31);
    const int k = kk * 64 + ((gp & 1) << 5) + ((l >> 5) << 4);
    const int4* p = (const int4*)(w + (size_t)n * IN_DIM + k);
    int4 a = p[0], b = p[1], c = p[2], d = p[3];
    int4 o;
    o.x = pack4(a.x, a.y, a.z, a.w);
    o.y = pack4(b.x, b.y, b.z, b.w);
    o.z = pack4(c.x, c.y, c.z, c.w);
    o.w = pack4(d.x, d.y, d.z, d.w);
    *(int4*)(w8t + (size_t)flat * 16) = o;
}

// ---- fused: x int32 -> int8 tiled layout  AND  T[m][r] = sum_k x[m][k]*A[r][k] ----
// block = 16 rows (grid 512); wave wv covers k in [wv*1024, wv*1024+1024)
__global__ __launch_bounds__(256) void pack_x_lora_kernel(const int* __restrict__ x,
                                                          const short* __restrict__ a16,
                                                          signed char* __restrict__ x8t,
                                                          float* __restrict__ T) {
    __shared__ float red[4 * 256];
    const int tid = threadIdx.x;
    const int lane = tid & 63, wv = tid >> 6;
    const int fr = lane & 15, fq = lane >> 4;
    const int m0 = blockIdx.x * 16;
    const int bm = m0 >> 8;
    const int g  = (m0 >> 5) & 7;
    const int l5 = (m0 & 16) + fr;           // row & 31
    const int row = m0 + fr;

    v4f acc = {0.f, 0.f, 0.f, 0.f};
#pragma unroll 2
    for (int kt = 0; kt < 32; ++kt) {
        const int k  = wv * 1024 + kt * 32 + fq * 8;
        const int4* xp = (const int4*)(x + (size_t)row * IN_DIM + k);
        int4 a = xp[0], b = xp[1];
        // packed store into tiled layout
        const int kk = k >> 6, c = (k >> 4) & 3, j8 = (k >> 3) & 1;
        int2 pk = make_int2(pack4(a.x, a.y, a.z, a.w), pack4(b.x, b.y, b.z, b.w));
        *(int2*)(x8t + ((size_t)((bm * 64 + kk) * 16 + g * 2 + (c >> 1))) * 1024 +
                 ((c & 1) * 32 + l5) * 16 + j8 * 8) = pk;
        // bf16 fragment (exact) + MFMA into T accumulator
        v8s xa;
        xa[0] = i2bf(a.x); xa[1] = i2bf(a.y); xa[2] = i2bf(a.z); xa[3] = i2bf(a.w);
        xa[4] = i2bf(b.x); xa[5] = i2bf(b.y); xa[6] = i2bf(b.z); xa[7] = i2bf(b.w);
        v8s aa = *(const v8s*)(a16 + (size_t)fr * IN_DIM + k);
        acc = __builtin_amdgcn_mfma_f32_16x16x32_bf16(xa, aa, acc, 0, 0, 0);
    }
    *(v4f*)&red[wv * 256 + lane * 4] = acc;
    __syncthreads();

    float s = red[tid] + red[256 + tid] + red[512 + tid] + red[768 + tid];
    const int sl = tid >> 2, j = tid & 3;
    const int r16 = ((sl >> 4) << 2) + j, col = sl & 15;  // C/D 16x16 layout
    T[(size_t)(m0 + r16) * 16 + col] = s;
}

// ---------------- i8 MFMA GEMM: 256x256 block, 128x128 wave tile, 32x32x32 ----------------
__global__ __launch_bounds__(256, 1) void q8_gemm_kernel(
    const signed char* __restrict__ x8t, const signed char* __restrict__ w8t,
    const float* __restrict__ Tp, const float* __restrict__ lbm,
    const float* __restrict__ bias, const float* __restrict__ xsc,
    const float* __restrict__ wsc, const int* __restrict__ gflag,
    float* __restrict__ out) {
    __shared__ __align__(16) signed char smem[65536];  // 2 x (A 16K | B 16K)

    const int tid  = threadIdx.x;
    const int lane = tid & 63;
    const int wv   = tid >> 6;
    const int wm   = wv >> 1, wn = wv & 1;
    // XCD-aware swizzle: XCD xcd works bm in [xcd*4, xcd*4+4) -> A set ~= 4MB L2
    const int b   = blockIdx.x;
    const int xcd = b & 7, rr = b >> 3;
    const int bm  = xcd * 4 + (rr & 3);   // [0,32)
    const int bn  = rr >> 2;              // [0,16)

    const int lofs = lane * 16;
    const signed char* Asrc = x8t + (size_t)bm * (64 * 16 * 1024);
    const signed char* Bsrc = w8t + (size_t)bn * (64 * 16 * 1024);
    signed char* ldsA = smem + wv * 4096;          // wave-uniform staging bases
    signed char* ldsB = smem + 16384 + wv * 4096;

    v16i acc[4][4];
    {
        v16i z;
#pragma unroll
        for (int i = 0; i < 16; ++i) z[i] = 0;
#pragma unroll
        for (int mt = 0; mt < 4; ++mt)
#pragma unroll
            for (int nt = 0; nt < 4; ++nt) acc[mt][nt] = z;
    }

    // prologue: stage tile 0 into buffer 0
    {
        const signed char* as = Asrc + (size_t)(wv * 4) * 1024 + lofs;
        const signed char* bs = Bsrc + (size_t)(wv * 4) * 1024 + lofs;
#pragma unroll
        for (int i = 0; i < 4; ++i) {
            async_cp16(as + i * 1024, ldsA + i * 1024);
            async_cp16(bs + i * 1024, ldsB + i * 1024);
        }
    }

    for (int kk = 0; kk < 64; ++kk) {
        __syncthreads();  // buffer kk&1 ready; other buffer's readers done
        if (kk + 1 < 64) {
            const int nb = (kk + 1) & 1;
            const signed char* as = Asrc + ((size_t)(kk + 1) * 16 + wv * 4) * 1024 + lofs;
            const signed char* bs = Bsrc + ((size_t)(kk + 1) * 16 + wv * 4) * 1024 + lofs;
#pragma unroll
            for (int i = 0; i < 4; ++i) {
                async_cp16(as + i * 1024, ldsA + nb * 32768 + i * 1024);
                async_cp16(bs + i * 1024, ldsB + nb * 32768 + i * 1024);
            }
        }
        const signed char* Ab = smem + (kk & 1) * 32768;
        const signed char* Bb = Ab + 16384;
#pragma unroll
        for (int s = 0; s < 2; ++s) {
            v4i av[4], bv[4];
#pragma unroll
            for (int mt = 0; mt < 4; ++mt)
                av[mt] = *(const v4i*)(Ab + ((wm * 4 + mt) * 2 + s) * 1024 + lofs);
#pragma unroll
            for (int nt = 0; nt < 4; ++nt)
                bv[nt] = *(const v4i*)(Bb + ((wn * 4 + nt) * 2 + s) * 1024 + lofs);
#pragma unroll
            for (int mt = 0; mt < 4; ++mt)
#pragma unroll
                for (int nt = 0; nt < 4; ++nt)
                    acc[mt][nt] = __builtin_amdgcn_mfma_i32_32x32x32_i8(
                        av[mt], bv[nt], acc[mt][nt], 0, 0, 0);
        }
    }

    // ---------------- epilogue: all operands straight from global (no LDS) ----------------
    const int mbase = bm * 256 + wm * 128;
    const int nbase = bn * 256 + wn * 128;
    const int l31 = lane & 31, lh = lane >> 5;
    const bool dg = (*gflag) != 0;

    v8s tf[4], bf[4];
#pragma unroll
    for (int mt = 0; mt < 4; ++mt) {
        const float* t0 = Tp + (size_t)(mbase + mt * 32 + l31) * 16 + lh * 8;
        v8s v;
#pragma unroll
        for (int j = 0; j < 8; ++j) v[j] = f2bf(t0[j]);
        tf[mt] = v;
    }
#pragma unroll
    for (int nt = 0; nt < 4; ++nt) {
        const float* bp = lbm + (size_t)(nbase + nt * 32 + l31) * 16 + lh * 8;
        v8s v;
#pragma unroll
        for (int j = 0; j < 8; ++j) v[j] = f2bf(bp[j]);
        bf[nt] = v;
    }
    float wsa[4], bba[4];
#pragma unroll
    for (int nt = 0; nt < 4; ++nt) {
        const int col = nbase + nt * 32 + l31;
        wsa[nt] = wsc[col];
        bba[nt] = bias[col];
    }

#pragma unroll
    for (int mt = 0; mt < 4; ++mt) {
        const int rowb = mbase + mt * 32 + lh * 4;
        float4 xs0 = *(const float4*)(xsc + rowb);
        float4 xs1 = *(const float4*)(xsc + rowb + 8);
        float4 xs2 = *(const float4*)(xsc + rowb + 16);
        float4 xs3 = *(const float4*)(xsc + rowb + 24);
        float xsv[16] = {xs0.x, xs0.y, xs0.z, xs0.w, xs1.x, xs1.y, xs1.z, xs1.w,
                         xs2.x, xs2.y, xs2.z, xs2.w, xs3.x, xs3.y, xs3.z, xs3.w};
#pragma unroll
        for (int nt = 0; nt < 4; ++nt) {
            v16f fa;
#pragma unroll
            for (int i = 0; i < 16; ++i) fa[i] = (float)acc[mt][nt][i] * wsa[nt];
            // fa += T-frag * lora_b-frag  (C/D layout shared with the i8 32x32 MFMA)
            fa = __builtin_amdgcn_mfma_f32_32x32x16_bf16(tf[mt], bf[nt], fa, 0, 0, 0);
            const int col = nbase + nt * 32 + l31;
#pragma unroll
            for (int r = 0; r < 16; ++r) {
                float u = fmaf(xsv[r], fa[r], bba[nt]);
                if (dg) u = gelu_tanh(u);
                out[(size_t)(rowb + (r & 3) + 8 * (r >> 2)) * OUT_DIM + col] = u;
            }
        }
    }
}

extern "C" void kernel_launch(void* const* d_in, const int* in_sizes, int n_in,
                              void* d_out, int out_size, void* d_ws, size_t ws_size,
                              hipStream_t stream) {
    const int*   x     = (const int*)d_in[0];
    const int*   wt    = (const int*)d_in[1];
    const float* bias  = (const float*)d_in[2];
    const float* xsc   = (const float*)d_in[3];
    const float* wsc   = (const float*)d_in[4];
    const float* la    = (const float*)d_in[5];
    const float* lb    = (const float*)d_in[6];
    const int*   gflag = (const int*)d_in[7];
    float* out = (float*)d_out;

    signed char* x8t = (signed char*)d_ws;
    signed char* w8t = x8t + (size_t)M_DIM * IN_DIM;
    float* T = (float*)(w8t + (size_t)OUT_DIM * IN_DIM);
    short* a16 = (short*)w8t;  // alias: consumed by pack_x_lora BEFORE pack_w writes w8t

    pack_a_kernel<<<16 * IN_DIM / (8 * 256), 256, 0, stream>>>(la, a16);
    pack_x_lora_kernel<<<M_DIM / 16, 256, 0, stream>>>(x, a16, x8t, T);
    pack_w_kernel<<<(size_t)OUT_DIM * IN_DIM / (16 * 256), 256, 0, stream>>>(wt, w8t);
    q8_gemm_kernel<<<(M_DIM / 256) * (OUT_DIM / 256), 256, 0, stream>>>(
        x8t, w8t, T, lb, bias, xsc, wsc, gflag, out);
}